// Round 4
// baseline (806.697 us; speedup 1.0000x reference)
//
#include <hip/hip_runtime.h>
#include <math.h>

#define HIDDEN 64
#define TARGET 10
#define EPB 2048          // edges per append/hist block (256 thr x 8)
#define NCH 8             // XCD channels
#define BUK 64            // dst nodes per bucket

static __device__ __forceinline__ unsigned short f2bf(float f) {
    unsigned int u = __float_as_uint(f);
    u = (u + 0x7fffu + ((u >> 16) & 1u)) >> 16;   // RNE
    return (unsigned short)u;
}
static __device__ __forceinline__ float bf2f(unsigned short v) {
    return __uint_as_float((unsigned int)v << 16);
}

// ---------------------------------------------------------------------------
// K1: precompute small tables.
//  tbl[0..63]   = hw_src ; tbl[64..127] = hw_dst
//  tbl[128..135]= tbl_travel ; tbl[136..138] = c0,c1,c2
// ---------------------------------------------------------------------------
__global__ void k_tables(const float* __restrict__ W_gat,
                         const float* __restrict__ att_src,
                         const float* __restrict__ att_dst,
                         const float* __restrict__ W_edge,
                         const float* __restrict__ att_edge,
                         const float* __restrict__ emb_travel,
                         float* __restrict__ tbl) {
    __shared__ float we_s[67];
    int t = threadIdx.x;
    if (t < 64) {
        float s1 = 0.f, s2 = 0.f;
        for (int j = 0; j < 64; j++) {
            float w = W_gat[t * 64 + j];
            s1 += w * att_src[j];
            s2 += w * att_dst[j];
        }
        tbl[t] = s1;
        tbl[64 + t] = s2;
    }
    if (t < 67) {
        float s = 0.f;
        for (int j = 0; j < 64; j++) s += W_edge[t * 64 + j] * att_edge[j];
        we_s[t] = s;
    }
    __syncthreads();
    if (t < 8) {
        float s = 0.f;
        for (int k = 0; k < 64; k++) s += emb_travel[t * 64 + k] * we_s[k];
        tbl[128 + t] = s;
    }
    if (t == 0) {
        tbl[136] = we_s[64];
        tbl[137] = we_s[65];
        tbl[138] = we_s[66];
    }
}

// ---------------------------------------------------------------------------
// K2: per-node, LDS-tiled register-blocked matmul (unchanged from r2).
// ---------------------------------------------------------------------------
__global__ __launch_bounds__(256) void k_nodes(
        const int* __restrict__ act, const int* __restrict__ loc,
        const float* __restrict__ emb_act,
        const float* __restrict__ emb_loc,
        const float* __restrict__ W_gat,
        const float* __restrict__ att_src,
        const float* __restrict__ att_dst,
        unsigned short* __restrict__ hb,
        float* __restrict__ a_src, float* __restrict__ a_dst,
        int N) {
    __shared__ float xs[64][68];
    __shared__ float Wl[64][68];
    __shared__ int acts[64], locs[64];
    int tid = threadIdx.x;
    int base = blockIdx.x * 64;

    for (int i = tid; i < 4096; i += 256) Wl[i >> 6][i & 63] = W_gat[i];
    if (tid < 64) {
        int n = base + tid;
        acts[tid] = (n < N) ? act[n] : 0;
        locs[tid] = (n < N) ? loc[n] : 0;
    }
    __syncthreads();

    for (int i = tid; i < 1024; i += 256) {
        int r = i >> 4, k4 = i & 15;
        int n = base + r;
        float4 v = make_float4(0.f, 0.f, 0.f, 0.f);
        if (n < N) {
            float4 a = ((const float4*)emb_act)[acts[r] * 16 + k4];
            float4 b = ((const float4*)emb_loc)[locs[r] * 16 + k4];
            v.x = fmaxf(a.x + b.x, 0.f);
            v.y = fmaxf(a.y + b.y, 0.f);
            v.z = fmaxf(a.z + b.z, 0.f);
            v.w = fmaxf(a.w + b.w, 0.f);
        }
        *(float4*)&xs[r][k4 * 4] = v;
    }
    __syncthreads();

    int tx = tid & 15, ty = tid >> 4;
    float acc[4][4];
#pragma unroll
    for (int i = 0; i < 4; i++)
#pragma unroll
        for (int j = 0; j < 4; j++) acc[i][j] = 0.f;

#pragma unroll 4
    for (int k4 = 0; k4 < 16; k4++) {
        float4 xv[4], wv[4];
#pragma unroll
        for (int i = 0; i < 4; i++) xv[i] = *(const float4*)&xs[ty * 4 + i][k4 * 4];
#pragma unroll
        for (int kk = 0; kk < 4; kk++) wv[kk] = *(const float4*)&Wl[k4 * 4 + kk][tx * 4];
#pragma unroll
        for (int i = 0; i < 4; i++) {
            float xk0 = xv[i].x, xk1 = xv[i].y, xk2 = xv[i].z, xk3 = xv[i].w;
            acc[i][0] += xk0 * wv[0].x + xk1 * wv[1].x + xk2 * wv[2].x + xk3 * wv[3].x;
            acc[i][1] += xk0 * wv[0].y + xk1 * wv[1].y + xk2 * wv[2].y + xk3 * wv[3].y;
            acc[i][2] += xk0 * wv[0].z + xk1 * wv[1].z + xk2 * wv[2].z + xk3 * wv[3].z;
            acc[i][3] += xk0 * wv[0].w + xk1 * wv[1].w + xk2 * wv[2].w + xk3 * wv[3].w;
        }
    }

#pragma unroll
    for (int i = 0; i < 4; i++) {
        int n = base + ty * 4 + i;
        if (n < N) {
            ushort4 hv;
            hv.x = f2bf(acc[i][0]); hv.y = f2bf(acc[i][1]);
            hv.z = f2bf(acc[i][2]); hv.w = f2bf(acc[i][3]);
            *(ushort4*)&hb[(size_t)n * 64 + tx * 4] = hv;
        }
    }

    float4 as4 = ((const float4*)att_src)[tx];
    float4 ad4 = ((const float4*)att_dst)[tx];
    float ps[4], pd[4];
#pragma unroll
    for (int i = 0; i < 4; i++) {
        ps[i] = acc[i][0] * as4.x + acc[i][1] * as4.y + acc[i][2] * as4.z + acc[i][3] * as4.w;
        pd[i] = acc[i][0] * ad4.x + acc[i][1] * ad4.y + acc[i][2] * ad4.z + acc[i][3] * ad4.w;
    }
#pragma unroll
    for (int off = 1; off < 16; off <<= 1) {
#pragma unroll
        for (int i = 0; i < 4; i++) {
            ps[i] += __shfl_xor(ps[i], off, 64);
            pd[i] += __shfl_xor(pd[i], off, 64);
        }
    }
    if (tx == 0) {
#pragma unroll
        for (int i = 0; i < 4; i++) {
            int n = base + ty * 4 + i;
            if (n < N) { a_src[n] = ps[i]; a_dst[n] = pd[i]; }
        }
    }
}

// ---------------------------------------------------------------------------
// K3a: per-(bucket,channel) histogram, LDS-aggregated.
// Chunking MUST match k_append: block b covers edges [b*EPB, (b+1)*EPB),
// channel = b & 7. gcnt[bucket*8 + ch].
// ---------------------------------------------------------------------------
__global__ __launch_bounds__(256) void k_histb(const int* __restrict__ dst, int E,
                                               int* __restrict__ gcnt, int NBUK) {
    __shared__ int c[1600];   // NBUK <= 1600 for N <= 102400
    int tid = threadIdx.x;
    int b = blockIdx.x;
    for (int i = tid; i < NBUK; i += 256) c[i] = 0;
    __syncthreads();
#pragma unroll
    for (int i = 0; i < EPB / 256; i++) {
        int e = b * EPB + i * 256 + tid;
        if (e < E) atomicAdd(&c[dst[e] >> 6], 1);
    }
    __syncthreads();
    int ch = b & (NCH - 1);
    for (int i = tid; i < NBUK; i += 256)
        if (c[i]) atomicAdd(&gcnt[i * NCH + ch], c[i]);
}

// ---------------------------------------------------------------------------
// K3b/c/d: two-level exclusive scan over M = NBUK*8 counts.
// ---------------------------------------------------------------------------
__global__ void k_scanA(const int* __restrict__ counts, int M,
                        int* __restrict__ rowstart, int* __restrict__ blocksum) {
    __shared__ int s[256];
    int tid = threadIdx.x;
    int i = blockIdx.x * 256 + tid;
    int c = (i < M) ? counts[i] : 0;
    s[tid] = c;
    __syncthreads();
    for (int off = 1; off < 256; off <<= 1) {
        int v = 0;
        if (tid >= off) v = s[tid - off];
        __syncthreads();
        if (tid >= off) s[tid] += v;
        __syncthreads();
    }
    if (i < M) rowstart[i] = s[tid] - c;
    if (tid == 255) blocksum[blockIdx.x] = s[255];
}

__global__ void k_scanB(int* __restrict__ blocksum, int NB) {
    __shared__ int s[1024];
    int tid = threadIdx.x;
    int c = (tid < NB) ? blocksum[tid] : 0;
    s[tid] = c;
    __syncthreads();
    for (int off = 1; off < 1024; off <<= 1) {
        int v = 0;
        if (tid >= off) v = s[tid - off];
        __syncthreads();
        if (tid >= off) s[tid] += v;
        __syncthreads();
    }
    if (tid < NB) blocksum[tid] = s[tid] - c;
}

__global__ void k_scanC(int* __restrict__ rowstart, int* __restrict__ cursor,
                        const int* __restrict__ blocksum, int M, int E) {
    int i = blockIdx.x * 256 + threadIdx.x;
    if (i < M) {
        int v = rowstart[i] + blocksum[blockIdx.x];
        rowstart[i] = v;
        cursor[i] = v;
    }
    if (i == 0) rowstart[M] = E;
}

// ---------------------------------------------------------------------------
// K3e: append edges to per-(bucket,channel) segments.
//  rec.x = src | (dst&63)<<20 ; rec.y = exp(leaky_relu(alpha)) bits
// Channel = blockIdx&7: under round-robin block->XCD dispatch, each segment
// is written by one XCD's L2 -> full-line writebacks (perf heuristic only).
// ---------------------------------------------------------------------------
__global__ __launch_bounds__(256) void k_append(
        const int* __restrict__ src, const int* __restrict__ dst,
        const int* __restrict__ travel,
        const float* __restrict__ dur,
        const float* __restrict__ tst,
        const float* __restrict__ tet,
        const float* __restrict__ a_src,
        const float* __restrict__ a_dst,
        const float* __restrict__ tbl,
        int* __restrict__ cursor,
        int2* __restrict__ epk, int E) {
    int tid = threadIdx.x;
    int b = blockIdx.x;
    int ch = b & (NCH - 1);
    float c0 = tbl[136], c1 = tbl[137], c2 = tbl[138];
#pragma unroll
    for (int i = 0; i < EPB / 256; i++) {
        int e = b * EPB + i * 256 + tid;
        if (e < E) {
            int s = src[e], d = dst[e];
            float al = a_src[s] + a_dst[d] + tbl[128 + travel[e]]
                     + c0 * dur[e] + c1 * tst[e] + c2 * tet[e];
            al = al > 0.f ? al : 0.2f * al;
            float ev = __expf(al);
            int pos = atomicAdd(&cursor[(d >> 6) * NCH + ch], 1);
            int2 p;
            p.x = s | ((d & 63) << 20);
            p.y = __float_as_int(ev);
            epk[pos] = p;
        }
    }
}

// ---------------------------------------------------------------------------
// K3f: bucketed gather with LDS accumulators. One block per 64-dst bucket.
// 4 waves x 4-edge quads; lane = grp(2b)|sub(4b): 16 lanes x ushort4 per edge.
// LDS acc stride 65 floats (bank spread). Fuses /denom + b_gat + relu AND
// global mean-pool partial sums (atomic into pooled_sums[graph]).
// ---------------------------------------------------------------------------
__global__ __launch_bounds__(256) void k_gather(
        const int2* __restrict__ epk,
        const int* __restrict__ rowstart,
        const ushort4* __restrict__ hb4,
        const float4* __restrict__ bg4,
        const int* __restrict__ batch,
        float* __restrict__ pooled_sums, int N) {
    __shared__ float accs[BUK * 65];
    __shared__ float den[BUK];
    int tid = threadIdx.x;
    int fb = blockIdx.x;

    for (int i = tid; i < BUK * 65; i += 256) accs[i] = 0.f;
    if (tid < BUK) den[tid] = 0.f;
    __syncthreads();

    int r0 = rowstart[fb * NCH];
    int r1 = rowstart[fb * NCH + NCH];
    int lane = tid & 63;
    int wave = tid >> 6;
    int grp = lane >> 4;
    int sub = lane & 15;

    for (int e0 = r0 + wave * 4; e0 < r1; e0 += 16) {
        int e = e0 + grp;
        if (e < r1) {
            int2 p = epk[e];
            float ev = __int_as_float(p.y);
            int s = p.x & 0xFFFFF;
            int dl = p.x >> 20;
            ushort4 hu = hb4[(size_t)s * 16 + sub];
            int base = dl * 65 + sub * 4;
            atomicAdd(&accs[base + 0], ev * bf2f(hu.x));
            atomicAdd(&accs[base + 1], ev * bf2f(hu.y));
            atomicAdd(&accs[base + 2], ev * bf2f(hu.z));
            atomicAdd(&accs[base + 3], ev * bf2f(hu.w));
            if (sub == 0) atomicAdd(&den[dl], ev);
        }
    }
    __syncthreads();

    // finalize: 256 threads = 64 nodes x 4 quads
    int dl = tid >> 2, q = tid & 3;
    int n = fb * BUK + dl;
    if (n < N) {
        float dn = den[dl];
        dn = dn > 1e-16f ? dn : 1e-16f;
        float inv = 1.f / dn;
        float4 bb = bg4[q];
        int base = dl * 65 + q * 4;
        float vx = fmaxf(accs[base + 0] * inv + bb.x, 0.f);
        float vy = fmaxf(accs[base + 1] * inv + bb.y, 0.f);
        float vz = fmaxf(accs[base + 2] * inv + bb.z, 0.f);
        float vw = fmaxf(accs[base + 3] * inv + bb.w, 0.f);
        int g = batch[n];
        float* ps = &pooled_sums[(size_t)g * 64 + q * 4];
        unsafeAtomicAdd(ps + 0, vx);
        unsafeAtomicAdd(ps + 1, vy);
        unsafeAtomicAdd(ps + 2, vz);
        unsafeAtomicAdd(ps + 3, vw);
    }
}

// ---------------------------------------------------------------------------
// K5: pooled = sums/cnt; logits = pooled @ W_fc + b_fc ; out = log_softmax.
// cnt per graph via binary search on sorted batch.
// ---------------------------------------------------------------------------
__global__ void k_fc(const float* __restrict__ pooled_sums,
                     const int* __restrict__ batch, int N,
                     const float* __restrict__ W_fc,
                     const float* __restrict__ b_fc,
                     float* __restrict__ out, int G) {
    int lane = threadIdx.x & 63;
    int wid = (blockIdx.x * blockDim.x + threadIdx.x) >> 6;
    int nw = (gridDim.x * blockDim.x) >> 6;
    for (int g = wid; g < G; g += nw) {
        int lo = 0, hi = N;
        while (lo < hi) { int mid = (lo + hi) >> 1; if (batch[mid] < g) lo = mid + 1; else hi = mid; }
        int start = lo;
        hi = N;
        while (lo < hi) { int mid = (lo + hi) >> 1; if (batch[mid] < g + 1) lo = mid + 1; else hi = mid; }
        float cnt = (float)(lo - start);
        float inv = 1.f / (cnt > 1.f ? cnt : 1.f);
        float p = pooled_sums[(size_t)g * 64 + lane] * inv;
        float logit[TARGET];
#pragma unroll
        for (int t = 0; t < TARGET; t++) {
            float v = p * W_fc[lane * TARGET + t];
#pragma unroll
            for (int o = 32; o > 0; o >>= 1) v += __shfl_xor(v, o, 64);
            logit[t] = v + b_fc[t];
        }
        float m = logit[0];
#pragma unroll
        for (int t = 1; t < TARGET; t++) m = fmaxf(m, logit[t]);
        float se = 0.f;
#pragma unroll
        for (int t = 0; t < TARGET; t++) se += expf(logit[t] - m);
        float lse = m + logf(se);
#pragma unroll
        for (int t = 0; t < TARGET; t++)
            if (lane == t) out[g * TARGET + t] = logit[t] - lse;
    }
}

extern "C" void kernel_launch(void* const* d_in, const int* in_sizes, int n_in,
                              void* d_out, int out_size, void* d_ws, size_t ws_size,
                              hipStream_t stream) {
    const int*   act        = (const int*)d_in[0];
    const int*   loc        = (const int*)d_in[1];
    const int*   travel     = (const int*)d_in[2];
    const float* dur        = (const float*)d_in[3];
    const float* tst        = (const float*)d_in[4];
    const float* tet        = (const float*)d_in[5];
    const int*   ei         = (const int*)d_in[6];
    const int*   batch      = (const int*)d_in[7];
    const float* emb_act    = (const float*)d_in[8];
    const float* emb_loc    = (const float*)d_in[9];
    const float* emb_travel = (const float*)d_in[10];
    const float* W_gat      = (const float*)d_in[11];
    const float* att_src    = (const float*)d_in[12];
    const float* att_dst    = (const float*)d_in[13];
    const float* W_edge     = (const float*)d_in[14];
    const float* att_edge   = (const float*)d_in[15];
    const float* b_gat      = (const float*)d_in[16];
    const float* W_fc       = (const float*)d_in[17];
    const float* b_fc       = (const float*)d_in[18];
    float* out = (float*)d_out;

    int N = in_sizes[0];
    int E = in_sizes[2];
    int G = out_size / TARGET;
    int NBUK = (N + BUK - 1) / BUK;       // 1563
    int M = NBUK * NCH;                   // 12504
    int NB2 = (M + 255) / 256;            // 49
    int NBLK_E = (E + EPB - 1) / EPB;     // 782

    float* ws = (float*)d_ws;
    size_t off = 0;
    float* tbl      = ws + off; off += 256;
    unsigned short* hb = (unsigned short*)(ws + off); off += (size_t)N * 32;
    float* a_src    = ws + off; off += N;
    float* a_dst    = ws + off; off += N;
    int*   gcnt     = (int*)(ws + off); off += M;
    int*   rowstart = (int*)(ws + off); off += M + 2;
    int*   cursor   = (int*)(ws + off); off += M;
    int*   blocksum = (int*)(ws + off); off += 1024;
    if (off & 1) off++;                   // 8B-align epk
    int2*  epk      = (int2*)(ws + off); off += (size_t)E * 2;
    float* pooled   = ws + off; off += (size_t)G * 64;

    hipMemsetAsync(gcnt, 0, (size_t)M * sizeof(int), stream);
    hipMemsetAsync(pooled, 0, (size_t)G * 64 * sizeof(float), stream);

    k_tables<<<1, 128, 0, stream>>>(W_gat, att_src, att_dst, W_edge, att_edge,
                                    emb_travel, tbl);
    k_nodes<<<(N + 63) / 64, 256, 0, stream>>>(act, loc, emb_act, emb_loc, W_gat,
                                               att_src, att_dst, hb, a_src, a_dst, N);
    k_histb<<<NBLK_E, 256, 0, stream>>>(ei + E, E, gcnt, NBUK);
    k_scanA<<<NB2, 256, 0, stream>>>(gcnt, M, rowstart, blocksum);
    k_scanB<<<1, 1024, 0, stream>>>(blocksum, NB2);
    k_scanC<<<NB2, 256, 0, stream>>>(rowstart, cursor, blocksum, M, E);
    k_append<<<NBLK_E, 256, 0, stream>>>(ei, ei + E, travel, dur, tst, tet,
                                         a_src, a_dst, tbl, cursor, epk, E);
    k_gather<<<NBUK, 256, 0, stream>>>(epk, rowstart,
                                       (const ushort4*)hb, (const float4*)b_gat,
                                       batch, pooled, N);
    k_fc<<<256, 256, 0, stream>>>(pooled, batch, N, W_fc, b_fc, out, G);
}

// Round 6
// 338.727 us; speedup vs baseline: 2.3816x; 2.3816x over previous
//
#include <hip/hip_runtime.h>
#include <math.h>

#define HIDDEN 64
#define TARGET 10
#define EPB 2048          // edges per append/hist block (256 thr x 8)
#define NCH 8             // XCD channels
#define BUK 64            // dst nodes per bucket
#define CHUNK 2048        // edges staged per in-LDS sort pass in k_gather

static __device__ __forceinline__ unsigned short f2bf(float f) {
    unsigned int u = __float_as_uint(f);
    u = (u + 0x7fffu + ((u >> 16) & 1u)) >> 16;   // RNE
    return (unsigned short)u;
}
static __device__ __forceinline__ float bf2f(unsigned short v) {
    return __uint_as_float((unsigned int)v << 16);
}

// ---------------------------------------------------------------------------
// K1: precompute small tables.
//  tbl[0..63]   = hw_src ; tbl[64..127] = hw_dst
//  tbl[128..135]= tbl_travel ; tbl[136..138] = c0,c1,c2
// ---------------------------------------------------------------------------
__global__ void k_tables(const float* __restrict__ W_gat,
                         const float* __restrict__ att_src,
                         const float* __restrict__ att_dst,
                         const float* __restrict__ W_edge,
                         const float* __restrict__ att_edge,
                         const float* __restrict__ emb_travel,
                         float* __restrict__ tbl) {
    __shared__ float we_s[67];
    int t = threadIdx.x;
    if (t < 64) {
        float s1 = 0.f, s2 = 0.f;
        for (int j = 0; j < 64; j++) {
            float w = W_gat[t * 64 + j];
            s1 += w * att_src[j];
            s2 += w * att_dst[j];
        }
        tbl[t] = s1;
        tbl[64 + t] = s2;
    }
    if (t < 67) {
        float s = 0.f;
        for (int j = 0; j < 64; j++) s += W_edge[t * 64 + j] * att_edge[j];
        we_s[t] = s;
    }
    __syncthreads();
    if (t < 8) {
        float s = 0.f;
        for (int k = 0; k < 64; k++) s += emb_travel[t * 64 + k] * we_s[k];
        tbl[128 + t] = s;
    }
    if (t == 0) {
        tbl[136] = we_s[64];
        tbl[137] = we_s[65];
        tbl[138] = we_s[66];
    }
}

// ---------------------------------------------------------------------------
// K2: per-node, LDS-tiled register-blocked matmul (unchanged from r2).
// ---------------------------------------------------------------------------
__global__ __launch_bounds__(256) void k_nodes(
        const int* __restrict__ act, const int* __restrict__ loc,
        const float* __restrict__ emb_act,
        const float* __restrict__ emb_loc,
        const float* __restrict__ W_gat,
        const float* __restrict__ att_src,
        const float* __restrict__ att_dst,
        unsigned short* __restrict__ hb,
        float* __restrict__ a_src, float* __restrict__ a_dst,
        int N) {
    __shared__ float xs[64][68];
    __shared__ float Wl[64][68];
    __shared__ int acts[64], locs[64];
    int tid = threadIdx.x;
    int base = blockIdx.x * 64;

    for (int i = tid; i < 4096; i += 256) Wl[i >> 6][i & 63] = W_gat[i];
    if (tid < 64) {
        int n = base + tid;
        acts[tid] = (n < N) ? act[n] : 0;
        locs[tid] = (n < N) ? loc[n] : 0;
    }
    __syncthreads();

    for (int i = tid; i < 1024; i += 256) {
        int r = i >> 4, k4 = i & 15;
        int n = base + r;
        float4 v = make_float4(0.f, 0.f, 0.f, 0.f);
        if (n < N) {
            float4 a = ((const float4*)emb_act)[acts[r] * 16 + k4];
            float4 b = ((const float4*)emb_loc)[locs[r] * 16 + k4];
            v.x = fmaxf(a.x + b.x, 0.f);
            v.y = fmaxf(a.y + b.y, 0.f);
            v.z = fmaxf(a.z + b.z, 0.f);
            v.w = fmaxf(a.w + b.w, 0.f);
        }
        *(float4*)&xs[r][k4 * 4] = v;
    }
    __syncthreads();

    int tx = tid & 15, ty = tid >> 4;
    float acc[4][4];
#pragma unroll
    for (int i = 0; i < 4; i++)
#pragma unroll
        for (int j = 0; j < 4; j++) acc[i][j] = 0.f;

#pragma unroll 4
    for (int k4 = 0; k4 < 16; k4++) {
        float4 xv[4], wv[4];
#pragma unroll
        for (int i = 0; i < 4; i++) xv[i] = *(const float4*)&xs[ty * 4 + i][k4 * 4];
#pragma unroll
        for (int kk = 0; kk < 4; kk++) wv[kk] = *(const float4*)&Wl[k4 * 4 + kk][tx * 4];
#pragma unroll
        for (int i = 0; i < 4; i++) {
            float xk0 = xv[i].x, xk1 = xv[i].y, xk2 = xv[i].z, xk3 = xv[i].w;
            acc[i][0] += xk0 * wv[0].x + xk1 * wv[1].x + xk2 * wv[2].x + xk3 * wv[3].x;
            acc[i][1] += xk0 * wv[0].y + xk1 * wv[1].y + xk2 * wv[2].y + xk3 * wv[3].y;
            acc[i][2] += xk0 * wv[0].z + xk1 * wv[1].z + xk2 * wv[2].z + xk3 * wv[3].z;
            acc[i][3] += xk0 * wv[0].w + xk1 * wv[1].w + xk2 * wv[2].w + xk3 * wv[3].w;
        }
    }

#pragma unroll
    for (int i = 0; i < 4; i++) {
        int n = base + ty * 4 + i;
        if (n < N) {
            ushort4 hv;
            hv.x = f2bf(acc[i][0]); hv.y = f2bf(acc[i][1]);
            hv.z = f2bf(acc[i][2]); hv.w = f2bf(acc[i][3]);
            *(ushort4*)&hb[(size_t)n * 64 + tx * 4] = hv;
        }
    }

    float4 as4 = ((const float4*)att_src)[tx];
    float4 ad4 = ((const float4*)att_dst)[tx];
    float ps[4], pd[4];
#pragma unroll
    for (int i = 0; i < 4; i++) {
        ps[i] = acc[i][0] * as4.x + acc[i][1] * as4.y + acc[i][2] * as4.z + acc[i][3] * as4.w;
        pd[i] = acc[i][0] * ad4.x + acc[i][1] * ad4.y + acc[i][2] * ad4.z + acc[i][3] * ad4.w;
    }
#pragma unroll
    for (int off = 1; off < 16; off <<= 1) {
#pragma unroll
        for (int i = 0; i < 4; i++) {
            ps[i] += __shfl_xor(ps[i], off, 64);
            pd[i] += __shfl_xor(pd[i], off, 64);
        }
    }
    if (tx == 0) {
#pragma unroll
        for (int i = 0; i < 4; i++) {
            int n = base + ty * 4 + i;
            if (n < N) { a_src[n] = ps[i]; a_dst[n] = pd[i]; }
        }
    }
}

// ---------------------------------------------------------------------------
// K3a: per-(bucket,channel) histogram, LDS-aggregated (unchanged from r3).
// ---------------------------------------------------------------------------
__global__ __launch_bounds__(256) void k_histb(const int* __restrict__ dst, int E,
                                               int* __restrict__ gcnt, int NBUK) {
    __shared__ int c[1600];
    int tid = threadIdx.x;
    int b = blockIdx.x;
    for (int i = tid; i < NBUK; i += 256) c[i] = 0;
    __syncthreads();
#pragma unroll
    for (int i = 0; i < EPB / 256; i++) {
        int e = b * EPB + i * 256 + tid;
        if (e < E) atomicAdd(&c[dst[e] >> 6], 1);
    }
    __syncthreads();
    int ch = b & (NCH - 1);
    for (int i = tid; i < NBUK; i += 256)
        if (c[i]) atomicAdd(&gcnt[i * NCH + ch], c[i]);
}

// ---------------------------------------------------------------------------
// K3b/c/d: two-level exclusive scan over M = NBUK*8 counts (unchanged).
// ---------------------------------------------------------------------------
__global__ void k_scanA(const int* __restrict__ counts, int M,
                        int* __restrict__ rowstart, int* __restrict__ blocksum) {
    __shared__ int s[256];
    int tid = threadIdx.x;
    int i = blockIdx.x * 256 + tid;
    int c = (i < M) ? counts[i] : 0;
    s[tid] = c;
    __syncthreads();
    for (int off = 1; off < 256; off <<= 1) {
        int v = 0;
        if (tid >= off) v = s[tid - off];
        __syncthreads();
        if (tid >= off) s[tid] += v;
        __syncthreads();
    }
    if (i < M) rowstart[i] = s[tid] - c;
    if (tid == 255) blocksum[blockIdx.x] = s[255];
}

__global__ void k_scanB(int* __restrict__ blocksum, int NB) {
    __shared__ int s[1024];
    int tid = threadIdx.x;
    int c = (tid < NB) ? blocksum[tid] : 0;
    s[tid] = c;
    __syncthreads();
    for (int off = 1; off < 1024; off <<= 1) {
        int v = 0;
        if (tid >= off) v = s[tid - off];
        __syncthreads();
        if (tid >= off) s[tid] += v;
        __syncthreads();
    }
    if (tid < NB) blocksum[tid] = s[tid] - c;
}

__global__ void k_scanC(int* __restrict__ rowstart, int* __restrict__ cursor,
                        const int* __restrict__ blocksum, int M, int E) {
    int i = blockIdx.x * 256 + threadIdx.x;
    if (i < M) {
        int v = rowstart[i] + blocksum[blockIdx.x];
        rowstart[i] = v;
        cursor[i] = v;
    }
    if (i == 0) rowstart[M] = E;
}

// ---------------------------------------------------------------------------
// K3e: append edges to per-(bucket,channel) segments (unchanged from r3).
// ---------------------------------------------------------------------------
__global__ __launch_bounds__(256) void k_append(
        const int* __restrict__ src, const int* __restrict__ dst,
        const int* __restrict__ travel,
        const float* __restrict__ dur,
        const float* __restrict__ tst,
        const float* __restrict__ tet,
        const float* __restrict__ a_src,
        const float* __restrict__ a_dst,
        const float* __restrict__ tbl,
        int* __restrict__ cursor,
        int2* __restrict__ epk, int E) {
    int tid = threadIdx.x;
    int b = blockIdx.x;
    int ch = b & (NCH - 1);
    float c0 = tbl[136], c1 = tbl[137], c2 = tbl[138];
#pragma unroll
    for (int i = 0; i < EPB / 256; i++) {
        int e = b * EPB + i * 256 + tid;
        if (e < E) {
            int s = src[e], d = dst[e];
            float al = a_src[s] + a_dst[d] + tbl[128 + travel[e]]
                     + c0 * dur[e] + c1 * tst[e] + c2 * tet[e];
            al = al > 0.f ? al : 0.2f * al;
            float ev = __expf(al);
            int pos = atomicAdd(&cursor[(d >> 6) * NCH + ch], 1);
            int2 p;
            p.x = s | ((d & 63) << 20);
            p.y = __float_as_int(ev);
            epk[pos] = p;
        }
    }
}

// ---------------------------------------------------------------------------
// K3f: bucketed gather, ATOMIC-FREE hot loop. One block per 64-dst bucket.
// Per CHUNK of the bucket's edge range: in-LDS counting sort by dst-local id
// (1 LDS atomic for hist + 1 for cursor per edge), then each of 4 waves
// exclusively owns dls {w, w+4, ...}: register accumulation (4 edges in
// flight x 16 subs x ushort4), shfl-xor reduce over grp bits, non-atomic add
// into accs[dl]. Finalize fuses /denom + b_gat + relu + mean-pool atomics.
// ---------------------------------------------------------------------------
__global__ __launch_bounds__(256) void k_gather(
        const int2* __restrict__ epk,
        const int* __restrict__ rowstart,
        const ushort4* __restrict__ hb4,
        const float4* __restrict__ bg4,
        const int* __restrict__ batch,
        float* __restrict__ pooled_sums, int N) {
    __shared__ float accs[BUK * 65];
    __shared__ float den[BUK];
    __shared__ int2 srec[CHUNK];
    __shared__ int cnt[BUK];
    __shared__ int cst[BUK + 1];
    __shared__ int cur[BUK];
    int tid = threadIdx.x;
    int fb = blockIdx.x;

    for (int i = tid; i < BUK * 65; i += 256) accs[i] = 0.f;
    if (tid < BUK) den[tid] = 0.f;
    __syncthreads();

    int r0 = rowstart[fb * NCH];
    int r1 = rowstart[fb * NCH + NCH];
    int lane = tid & 63;
    int wave = tid >> 6;
    int grp = lane >> 4;
    int sub = lane & 15;

    for (int c0 = r0; c0 < r1; c0 += CHUNK) {
        int cc = r1 - c0;
        if (cc > CHUNK) cc = CHUNK;
        if (tid < BUK) cnt[tid] = 0;
        __syncthreads();
        // 1) histogram of dst-local ids for this chunk
        for (int i = tid; i < cc; i += 256) {
            int2 p = epk[c0 + i];
            atomicAdd(&cnt[p.x >> 20], 1);
        }
        __syncthreads();
        // 2) exclusive scan of 64 counters (wave 0)
        if (tid < 64) {
            int c = cnt[tid];
            int v = c;
#pragma unroll
            for (int off = 1; off < 64; off <<= 1) {
                int t = __shfl_up(v, off, 64);
                if (tid >= off) v += t;
            }
            cst[tid] = v - c;
            cur[tid] = v - c;
            if (tid == 63) cst[64] = v;
        }
        __syncthreads();
        // 3) scatter records into dl-sorted LDS array
        for (int i = tid; i < cc; i += 256) {
            int2 p = epk[c0 + i];
            int pos = atomicAdd(&cur[p.x >> 20], 1);
            srec[pos] = p;
        }
        __syncthreads();
        // 4) per-dl register accumulation; wave owns dls {wave, wave+4, ...}
        for (int dl = wave; dl < BUK; dl += 4) {
            int s0 = cst[dl], s1 = cst[dl + 1];
            if (s0 == s1) continue;
            float ax = 0.f, ay = 0.f, az = 0.f, aw = 0.f, dv = 0.f;
            for (int e0 = s0; e0 < s1; e0 += 4) {
                int e = e0 + grp;
                if (e < s1) {
                    int2 p = srec[e];
                    float ev = __int_as_float(p.y);
                    int s = p.x & 0xFFFFF;
                    ushort4 hu = hb4[(size_t)s * 16 + sub];
                    ax += ev * bf2f(hu.x); ay += ev * bf2f(hu.y);
                    az += ev * bf2f(hu.z); aw += ev * bf2f(hu.w);
                    dv += ev;
                }
            }
#pragma unroll
            for (int off = 16; off < 64; off <<= 1) {
                ax += __shfl_xor(ax, off, 64);
                ay += __shfl_xor(ay, off, 64);
                az += __shfl_xor(az, off, 64);
                aw += __shfl_xor(aw, off, 64);
                dv += __shfl_xor(dv, off, 64);
            }
            if (grp == 0) {   // lane < 16; sub == lane; this wave owns dl
                int base = dl * 65 + sub * 4;
                accs[base + 0] += ax;
                accs[base + 1] += ay;
                accs[base + 2] += az;
                accs[base + 3] += aw;
                if (sub == 0) den[dl] += dv;
            }
        }
        __syncthreads();
    }

    // finalize: 256 threads = 64 nodes x 4 quads
    int dl = tid >> 2, q = tid & 3;
    int n = fb * BUK + dl;
    if (n < N) {
        float dn = den[dl];
        dn = dn > 1e-16f ? dn : 1e-16f;
        float inv = 1.f / dn;
        float4 bb = bg4[q];
        int base = dl * 65 + q * 4;
        float vx = fmaxf(accs[base + 0] * inv + bb.x, 0.f);
        float vy = fmaxf(accs[base + 1] * inv + bb.y, 0.f);
        float vz = fmaxf(accs[base + 2] * inv + bb.z, 0.f);
        float vw = fmaxf(accs[base + 3] * inv + bb.w, 0.f);
        int g = batch[n];
        float* ps = &pooled_sums[(size_t)g * 64 + q * 4];
        unsafeAtomicAdd(ps + 0, vx);
        unsafeAtomicAdd(ps + 1, vy);
        unsafeAtomicAdd(ps + 2, vz);
        unsafeAtomicAdd(ps + 3, vw);
    }
}

// ---------------------------------------------------------------------------
// K5: pooled = sums/cnt; logits = pooled @ W_fc + b_fc ; out = log_softmax.
// ---------------------------------------------------------------------------
__global__ void k_fc(const float* __restrict__ pooled_sums,
                     const int* __restrict__ batch, int N,
                     const float* __restrict__ W_fc,
                     const float* __restrict__ b_fc,
                     float* __restrict__ out, int G) {
    int lane = threadIdx.x & 63;
    int wid = (blockIdx.x * blockDim.x + threadIdx.x) >> 6;
    int nw = (gridDim.x * blockDim.x) >> 6;
    for (int g = wid; g < G; g += nw) {
        int lo = 0, hi = N;
        while (lo < hi) { int mid = (lo + hi) >> 1; if (batch[mid] < g) lo = mid + 1; else hi = mid; }
        int start = lo;
        hi = N;
        while (lo < hi) { int mid = (lo + hi) >> 1; if (batch[mid] < g + 1) lo = mid + 1; else hi = mid; }
        float cnt = (float)(lo - start);
        float inv = 1.f / (cnt > 1.f ? cnt : 1.f);
        float p = pooled_sums[(size_t)g * 64 + lane] * inv;
        float logit[TARGET];
#pragma unroll
        for (int t = 0; t < TARGET; t++) {
            float v = p * W_fc[lane * TARGET + t];
#pragma unroll
            for (int o = 32; o > 0; o >>= 1) v += __shfl_xor(v, o, 64);
            logit[t] = v + b_fc[t];
        }
        float m = logit[0];
#pragma unroll
        for (int t = 1; t < TARGET; t++) m = fmaxf(m, logit[t]);
        float se = 0.f;
#pragma unroll
        for (int t = 0; t < TARGET; t++) se += expf(logit[t] - m);
        float lse = m + logf(se);
#pragma unroll
        for (int t = 0; t < TARGET; t++)
            if (lane == t) out[g * TARGET + t] = logit[t] - lse;
    }
}

extern "C" void kernel_launch(void* const* d_in, const int* in_sizes, int n_in,
                              void* d_out, int out_size, void* d_ws, size_t ws_size,
                              hipStream_t stream) {
    const int*   act        = (const int*)d_in[0];
    const int*   loc        = (const int*)d_in[1];
    const int*   travel     = (const int*)d_in[2];
    const float* dur        = (const float*)d_in[3];
    const float* tst        = (const float*)d_in[4];
    const float* tet        = (const float*)d_in[5];
    const int*   ei         = (const int*)d_in[6];
    const int*   batch      = (const int*)d_in[7];
    const float* emb_act    = (const float*)d_in[8];
    const float* emb_loc    = (const float*)d_in[9];
    const float* emb_travel = (const float*)d_in[10];
    const float* W_gat      = (const float*)d_in[11];
    const float* att_src    = (const float*)d_in[12];
    const float* att_dst    = (const float*)d_in[13];
    const float* W_edge     = (const float*)d_in[14];
    const float* att_edge   = (const float*)d_in[15];
    const float* b_gat      = (const float*)d_in[16];
    const float* W_fc       = (const float*)d_in[17];
    const float* b_fc       = (const float*)d_in[18];
    float* out = (float*)d_out;

    int N = in_sizes[0];
    int E = in_sizes[2];
    int G = out_size / TARGET;
    int NBUK = (N + BUK - 1) / BUK;       // 1563
    int M = NBUK * NCH;                   // 12504
    int NB2 = (M + 255) / 256;            // 49
    int NBLK_E = (E + EPB - 1) / EPB;     // 782

    float* ws = (float*)d_ws;
    size_t off = 0;
    float* tbl      = ws + off; off += 256;
    unsigned short* hb = (unsigned short*)(ws + off); off += (size_t)N * 32;
    float* a_src    = ws + off; off += N;
    float* a_dst    = ws + off; off += N;
    int*   gcnt     = (int*)(ws + off); off += M;
    int*   rowstart = (int*)(ws + off); off += M + 2;
    int*   cursor   = (int*)(ws + off); off += M;
    int*   blocksum = (int*)(ws + off); off += 1024;
    if (off & 1) off++;                   // 8B-align epk
    int2*  epk      = (int2*)(ws + off); off += (size_t)E * 2;
    float* pooled   = ws + off; off += (size_t)G * 64;

    hipMemsetAsync(gcnt, 0, (size_t)M * sizeof(int), stream);
    hipMemsetAsync(pooled, 0, (size_t)G * 64 * sizeof(float), stream);

    k_tables<<<1, 128, 0, stream>>>(W_gat, att_src, att_dst, W_edge, att_edge,
                                    emb_travel, tbl);
    k_nodes<<<(N + 63) / 64, 256, 0, stream>>>(act, loc, emb_act, emb_loc, W_gat,
                                               att_src, att_dst, hb, a_src, a_dst, N);
    k_histb<<<NBLK_E, 256, 0, stream>>>(ei + E, E, gcnt, NBUK);
    k_scanA<<<NB2, 256, 0, stream>>>(gcnt, M, rowstart, blocksum);
    k_scanB<<<1, 1024, 0, stream>>>(blocksum, NB2);
    k_scanC<<<NB2, 256, 0, stream>>>(rowstart, cursor, blocksum, M, E);
    k_append<<<NBLK_E, 256, 0, stream>>>(ei, ei + E, travel, dur, tst, tet,
                                         a_src, a_dst, tbl, cursor, epk, E);
    k_gather<<<NBUK, 256, 0, stream>>>(epk, rowstart,
                                       (const ushort4*)hb, (const float4*)b_gat,
                                       batch, pooled, N);
    k_fc<<<256, 256, 0, stream>>>(pooled, batch, N, W_fc, b_fc, out, G);
}